// Round 3
// baseline (655.579 us; speedup 1.0000x reference)
//
#include <hip/hip_runtime.h>

typedef unsigned short ushort_t;
typedef unsigned int uint_t;

typedef __bf16 bf16x8 __attribute__((ext_vector_type(8)));
typedef float f32x4 __attribute__((ext_vector_type(4)));

union BFU { ushort_t u; __bf16 h; };

__device__ __forceinline__ float bf2f(uint_t u) {
    union { uint_t i; float f; } v; v.i = u << 16; return v.f;
}
__device__ __forceinline__ ushort_t f2bf(float f) {
    union { float f; uint_t i; } v; v.f = f;
    uint_t r = v.i + 0x7fffu + ((v.i >> 16) & 1u);
    return (ushort_t)(r >> 16);
}
// mode: 1 = bf16 storage, 0 = fp32 storage
__device__ __forceinline__ float loadF(const void* p, size_t i, int isBf16) {
    return isBf16 ? bf2f((uint_t)((const ushort_t*)p)[i]) : ((const float*)p)[i];
}

// ---------------- dtype detection ----------------
// flags[0..10]: x,W1,b1,W2,b2,W3,b3,Wres,bres,Wlin,blin  (1=bf16, 0=fp32)
// flags[11]: edge_index is int64 (1) or int32 (0)
struct DetectArgs {
    const void* t[11];
    int elems[11];
    const int* ei;
    int* flags;
};

__global__ void k_detect(DetectArgs a) {
    int t = threadIdx.x;
    if (t < 11) {
        const uint_t* w = (const uint_t*)a.t[t];
        int n = a.elems[t] / 2; if (n > 64) n = 64;   // conservative (bf16 buffer size)
        int cnt = 0;
        for (int i = 0; i < n; ++i) {
            uint_t field = (w[i] >> 7) & 0xFFu;       // exponent field of low bf16
            cnt += (field >= 100u && field <= 135u);
        }
        a.flags[t] = (cnt * 10 >= n * 6) ? 1 : 0;     // majority -> bf16
    } else if (t == 11) {
        int nz = 0;
        for (int i = 0; i < 64; ++i) nz += (a.ei[2 * i + 1] != 0);
        a.flags[11] = (nz == 0) ? 1 : 0;              // all-zero odd words -> int64
    }
}

// ---------------- preprocessing ----------------

__global__ void k_zero(int* p, int n) {
    int i = blockIdx.x * blockDim.x + threadIdx.x;
    if (i < n) p[i] = 0;
}

__global__ void k_deg(const int* __restrict__ ei, int E, int N,
                      const int* __restrict__ flags, int* __restrict__ deg) {
    int e = blockIdx.x * blockDim.x + threadIdx.x;
    if (e < E) {
        int is64 = flags[11];
        int d = is64 ? ei[2 * E + 2 * e] : ei[E + e];
        if ((unsigned)d < (unsigned)N) atomicAdd(&deg[d], 1);
    }
}

__global__ __launch_bounds__(1024) void k_scan(const int* __restrict__ deg,
                                               int* __restrict__ row_ptr,
                                               float* __restrict__ dinv,
                                               float* __restrict__ nself, int n) {
    __shared__ int sums[1024];
    int t = threadIdx.x;
    const int C = (n + 1023) / 1024;
    int base = t * C;
    int local = 0;
    for (int i = 0; i < C; ++i) {
        int idx = base + i;
        if (idx < n) local += deg[idx];
    }
    sums[t] = local;
    __syncthreads();
    for (int off = 1; off < 1024; off <<= 1) {
        int v = (t >= off) ? sums[t - off] : 0;
        __syncthreads();
        sums[t] += v;
        __syncthreads();
    }
    int run = (t == 0) ? 0 : sums[t - 1];
    for (int i = 0; i < C; ++i) {
        int idx = base + i;
        if (idx < n) {
            row_ptr[idx] = run;
            int d = deg[idx];
            run += d;
            float df = (float)d + 1.0f;
            dinv[idx] = rsqrtf(df);
            nself[idx] = 1.0f / df;
        }
    }
    if (t == 1023) row_ptr[n] = run;
}

__global__ void k_fill(const int* __restrict__ ei, int E, int N,
                       const int* __restrict__ flags,
                       const int* __restrict__ row_ptr, int* __restrict__ cnt,
                       int* __restrict__ col) {
    int e = blockIdx.x * blockDim.x + threadIdx.x;
    if (e < E) {
        int is64 = flags[11];
        int s = is64 ? ei[2 * e] : ei[e];
        int d = is64 ? ei[2 * E + 2 * e] : ei[E + e];
        if ((unsigned)d < (unsigned)N) {
            int pos = row_ptr[d] + atomicAdd(&cnt[d], 1);
            col[pos] = ((unsigned)s < (unsigned)N) ? s : 0;
        }
    }
}

// transpose + canonicalize weights to bf16: W[K x F] -> WT[F x K]
__global__ void k_pack(const void* __restrict__ W1, const void* __restrict__ W2,
                       const void* __restrict__ W3, const void* __restrict__ Wr,
                       const void* __restrict__ Wl, const int* __restrict__ flags,
                       ushort_t* __restrict__ T1, ushort_t* __restrict__ T2,
                       ushort_t* __restrict__ T3, ushort_t* __restrict__ Tr,
                       ushort_t* __restrict__ Tl) {
    int i = blockIdx.x * blockDim.x + threadIdx.x;
    const int SQ = 128 * 128;
    if (i < 4 * SQ) {
        int m = i / SQ, r = i % SQ;
        int k = r / 128, f = r % 128;
        const void* W = (m == 0) ? W1 : (m == 1) ? W2 : (m == 2) ? W3 : Wr;
        ushort_t* T = (m == 0) ? T1 : (m == 1) ? T2 : (m == 2) ? T3 : Tr;
        int fid = (m == 0) ? 1 : (m == 1) ? 3 : (m == 2) ? 5 : 7;
        T[f * 128 + k] = f2bf(loadF(W, (size_t)k * 128 + f, flags[fid]));
    } else if (i < 4 * SQ + 128 * 64) {
        int r = i - 4 * SQ;
        int k = r / 64, f = r % 64;
        Tl[f * 128 + k] = f2bf(loadF(Wl, (size_t)k * 64 + f, flags[9]));
    }
}

// ---------------- GEMM: A[M x 128] @ W[128 x (NCT*16)] ----------------
// aFid >= 0: A dtype from flags[aFid]; else fixed aFix. Same for C via cFid/cFix.
template <int NCT>
__global__ __launch_bounds__(256) void k_gemm(const void* __restrict__ A, int aFid, int aFix,
                                              const ushort_t* __restrict__ WT,
                                              const void* __restrict__ bias, int bFid,
                                              void* __restrict__ C, int cFid, int cFix,
                                              int M, const int* __restrict__ flags) {
    const int K = 128;
    const int F = NCT * 16;
    int wave = threadIdx.x >> 6;
    int lane = threadIdx.x & 63;
    int quad = lane >> 4;
    int l16 = lane & 15;
    int rowBase = blockIdx.x * 64 + wave * 16;

    int a16 = (aFid >= 0) ? flags[aFid] : aFix;
    int c16 = (cFid >= 0) ? flags[cFid] : cFix;

    int arow = rowBase + l16;
    if (arow >= M) arow = M - 1;

    f32x4 acc[NCT];
#pragma unroll
    for (int c = 0; c < NCT; ++c) acc[c] = (f32x4){0.f, 0.f, 0.f, 0.f};

    const ushort_t* aptr16 = (const ushort_t*)A + (size_t)arow * K + quad * 8;
    const float*    aptr32 = (const float*)A + (size_t)arow * K + quad * 8;

#pragma unroll
    for (int kk = 0; kk < K; kk += 32) {
        bf16x8 a;
        if (a16) {
            a = *(const bf16x8*)(aptr16 + kk);
        } else {
            const f32x4* p = (const f32x4*)(aptr32 + kk);
            f32x4 u0 = p[0], u1 = p[1];
#pragma unroll
            for (int j = 0; j < 4; ++j) {
                BFU e0; e0.u = f2bf(u0[j]); a[j] = e0.h;
                BFU e1; e1.u = f2bf(u1[j]); a[j + 4] = e1.h;
            }
        }
#pragma unroll
        for (int c = 0; c < NCT; ++c) {
            const ushort_t* bp = WT + (size_t)(c * 16 + l16) * K + quad * 8 + kk;
            bf16x8 b = *(const bf16x8*)bp;
            acc[c] = __builtin_amdgcn_mfma_f32_16x16x32_bf16(a, b, acc[c], 0, 0, 0);
        }
    }

    int bf = (bias && bFid >= 0) ? flags[bFid] : 1;
#pragma unroll
    for (int c = 0; c < NCT; ++c) {
        int colg = c * 16 + l16;
        float bv = bias ? loadF(bias, colg, bf) : 0.0f;
#pragma unroll
        for (int r = 0; r < 4; ++r) {
            int row = rowBase + quad * 4 + r;
            if (row < M) {
                float v = acc[c][r] + bv;
                if (c16) ((ushort_t*)C)[(size_t)row * F + colg] = f2bf(v);
                else     ((float*)C)[(size_t)row * F + colg] = v;
            }
        }
    }
}

// ---------------- aggregation: one wave per node, lane owns 2 features ----------------
__global__ __launch_bounds__(256) void k_agg(const void* __restrict__ H, int h16,
                                             const int* __restrict__ row_ptr,
                                             const int* __restrict__ col,
                                             const float* __restrict__ dinv,
                                             const float* __restrict__ nself,
                                             const void* __restrict__ bias, int bFid,
                                             const void* __restrict__ other, int o16,
                                             void* __restrict__ Out, int out16,
                                             int n, const int* __restrict__ flags) {
    int node = (blockIdx.x * blockDim.x + threadIdx.x) >> 6;
    if (node >= n) return;
    int lane = threadIdx.x & 63;
    int f = lane * 2;

    float dn = dinv[node];
    float ns = nself[node];
    size_t nidx = (size_t)node * 128 + f;

    float a0, a1;
    if (h16) {
        uint_t hv = *(const uint_t*)((const ushort_t*)H + nidx);
        a0 = bf2f(hv & 0xffffu) * ns;
        a1 = bf2f(hv >> 16) * ns;
    } else {
        const float* p = (const float*)H + nidx;
        a0 = p[0] * ns;
        a1 = p[1] * ns;
    }

    int beg = row_ptr[node], end = row_ptr[node + 1];
    if (h16) {
        for (int i = beg; i < end; ++i) {
            int s = col[i];
            float w = dinv[s] * dn;
            uint_t v = *(const uint_t*)((const ushort_t*)H + (size_t)s * 128 + f);
            a0 = fmaf(bf2f(v & 0xffffu), w, a0);
            a1 = fmaf(bf2f(v >> 16), w, a1);
        }
    } else {
        for (int i = beg; i < end; ++i) {
            int s = col[i];
            float w = dinv[s] * dn;
            const float* p = (const float*)H + (size_t)s * 128 + f;
            a0 = fmaf(p[0], w, a0);
            a1 = fmaf(p[1], w, a1);
        }
    }

    int bfm = flags[bFid];
    a0 += loadF(bias, f, bfm);
    a1 += loadF(bias, f + 1, bfm);
    if (other) {
        a0 += loadF(other, nidx, o16);
        a1 += loadF(other, nidx + 1, o16);
    }
    a0 = fmaxf(a0, 0.0f);
    a1 = fmaxf(a1, 0.0f);
    if (out16) {
        uint_t outv = (uint_t)f2bf(a0) | ((uint_t)f2bf(a1) << 16);
        *(uint_t*)((ushort_t*)Out + nidx) = outv;
    } else {
        float* p = (float*)Out + nidx;
        p[0] = a0;
        p[1] = a1;
    }
}

// ---------------- launch ----------------

extern "C" void kernel_launch(void* const* d_in, const int* in_sizes, int n_in,
                              void* d_out, int out_size, void* d_ws, size_t ws_size,
                              hipStream_t stream) {
    const int N = in_sizes[0] / 128;
    const int E = in_sizes[1] / 2;

    const void* x  = d_in[0];
    const int*  ei = (const int*)d_in[1];

    char* ws = (char*)d_ws;
    size_t used = 0;
    auto alloc = [&](size_t bytes) {
        char* p = ws + used;
        used += (bytes + 255) & ~(size_t)255;
        return p;
    };

    int*   flags   = (int*)alloc(64 * 4);
    int*   deg     = (int*)alloc((size_t)2 * N * 4);
    int*   cnt     = deg + N;
    int*   row_ptr = (int*)alloc((size_t)(N + 1) * 4);
    float* dinv    = (float*)alloc((size_t)N * 4);
    float* nself   = (float*)alloc((size_t)N * 4);
    int*   colv    = (int*)alloc((size_t)E * 4);
    ushort_t* T1   = (ushort_t*)alloc(128 * 128 * 2);
    ushort_t* T2   = (ushort_t*)alloc(128 * 128 * 2);
    ushort_t* T3   = (ushort_t*)alloc(128 * 128 * 2);
    ushort_t* Tres = (ushort_t*)alloc(128 * 128 * 2);
    ushort_t* Tlin = (ushort_t*)alloc(128 * 64 * 2);

    // intermediates: fp32 if workspace allows (better precision), else bf16
    size_t remain = (ws_size > used) ? ws_size - used : 0;
    size_t needF32 = 3 * (((size_t)N * 128 * 4 + 255) & ~(size_t)255);
    int im = (remain >= needF32) ? 0 : 1;   // 0=fp32 intermediates, 1=bf16
    size_t esz = im ? 2 : 4;
    void* Hbuf = alloc((size_t)N * 128 * esz);
    void* O1   = alloc((size_t)N * 128 * esz);
    void* Xres = alloc((size_t)N * 128 * esz);

    if (used > ws_size) return;   // diagnostic: 0.159 absmax if ws too small

    DetectArgs da;
    for (int i = 0; i < 11; ++i) { da.t[i] = d_in[i == 0 ? 0 : i + 1]; da.elems[i] = in_sizes[i == 0 ? 0 : i + 1]; }
    da.ei = ei;
    da.flags = flags;

    const int B = 256;
    int gZero = (2 * N + B - 1) / B;
    int gE    = (E + B - 1) / B;
    int gPack = (4 * 128 * 128 + 128 * 64 + B - 1) / B;
    int gGemm = (N + 63) / 64;
    int gAgg  = (N + 3) / 4;

    k_detect<<<1, 64, 0, stream>>>(da);
    k_zero<<<gZero, B, 0, stream>>>(deg, 2 * N);
    k_pack<<<gPack, B, 0, stream>>>(d_in[2], d_in[4], d_in[6], d_in[8], d_in[10], flags,
                                    T1, T2, T3, Tres, Tlin);
    k_deg<<<gE, B, 0, stream>>>(ei, E, N, flags, deg);
    k_scan<<<1, 1024, 0, stream>>>(deg, row_ptr, dinv, nself, N);
    k_fill<<<gE, B, 0, stream>>>(ei, E, N, flags, row_ptr, cnt, colv);

    // layer 1: H = x@W1 ; Xres = x@Wres + bres ; O1 = relu(agg(H) + b1 + Xres)
    k_gemm<8><<<gGemm, B, 0, stream>>>(x, 0, 0, T1, nullptr, -1, Hbuf, -1, im, N, flags);
    k_gemm<8><<<gGemm, B, 0, stream>>>(x, 0, 0, Tres, d_in[9], 8, Xres, -1, im, N, flags);
    k_agg<<<gAgg, B, 0, stream>>>(Hbuf, im, row_ptr, colv, dinv, nself, d_in[3], 2,
                                  Xres, im, O1, im, N, flags);

    // layer 2
    k_gemm<8><<<gGemm, B, 0, stream>>>(O1, -1, im, T2, nullptr, -1, Hbuf, -1, im, N, flags);
    k_agg<<<gAgg, B, 0, stream>>>(Hbuf, im, row_ptr, colv, dinv, nself, d_in[5], 4,
                                  nullptr, 0, Xres, im, N, flags);

    // layer 3
    k_gemm<8><<<gGemm, B, 0, stream>>>(Xres, -1, im, T3, nullptr, -1, Hbuf, -1, im, N, flags);
    k_agg<<<gAgg, B, 0, stream>>>(Hbuf, im, row_ptr, colv, dinv, nself, d_in[7], 6,
                                  nullptr, 0, O1, im, N, flags);

    // final: out = O3@Wlin + blin — output dtype follows x's storage dtype
    k_gemm<4><<<gGemm, B, 0, stream>>>(O1, -1, im, Tlin, d_in[11], 10,
                                       d_out, 0, 0, N, flags);
}

// Round 4
// 521.753 us; speedup vs baseline: 1.2565x; 1.2565x over previous
//
#include <hip/hip_runtime.h>

typedef unsigned short ushort_t;
typedef unsigned int uint_t;

typedef __bf16 bf16x8 __attribute__((ext_vector_type(8)));
typedef float f32x4 __attribute__((ext_vector_type(4)));

union BFU { ushort_t u; __bf16 h; };

__device__ __forceinline__ float bf2f(uint_t u) {
    union { uint_t i; float f; } v; v.i = u << 16; return v.f;
}
__device__ __forceinline__ ushort_t f2bf(float f) {
    union { float f; uint_t i; } v; v.f = f;
    uint_t r = v.i + 0x7fffu + ((v.i >> 16) & 1u);
    return (ushort_t)(r >> 16);
}
// mode: 1 = bf16 storage, 0 = fp32 storage
__device__ __forceinline__ float loadF(const void* p, size_t i, int isBf16) {
    return isBf16 ? bf2f((uint_t)((const ushort_t*)p)[i]) : ((const float*)p)[i];
}

// ---------------- dtype detection ----------------
// flags[0..10]: x,W1,b1,W2,b2,W3,b3,Wres,bres,Wlin,blin  (1=bf16, 0=fp32)
// flags[11]: edge_index is int64 (1) or int32 (0)
struct DetectArgs {
    const void* t[11];
    int elems[11];
    const int* ei;
    int* flags;
};

__global__ void k_detect(DetectArgs a) {
    int t = threadIdx.x;
    if (t < 11) {
        const uint_t* w = (const uint_t*)a.t[t];
        int n = a.elems[t] / 2; if (n > 64) n = 64;
        int cnt = 0;
        for (int i = 0; i < n; ++i) {
            uint_t field = (w[i] >> 7) & 0xFFu;
            cnt += (field >= 100u && field <= 135u);
        }
        a.flags[t] = (cnt * 10 >= n * 6) ? 1 : 0;
    } else if (t == 11) {
        int nz = 0;
        for (int i = 0; i < 64; ++i) nz += (a.ei[2 * i + 1] != 0);
        a.flags[11] = (nz == 0) ? 1 : 0;
    }
}

// ---------------- preprocessing ----------------

__global__ void k_zero(int* p, int n) {
    int i = blockIdx.x * blockDim.x + threadIdx.x;
    if (i < n) p[i] = 0;
}

__global__ void k_deg(const int* __restrict__ ei, int E, int N,
                      const int* __restrict__ flags, int* __restrict__ deg) {
    int e = blockIdx.x * blockDim.x + threadIdx.x;
    if (e < E) {
        int is64 = flags[11];
        int d = is64 ? ei[2 * E + 2 * e] : ei[E + e];
        if ((unsigned)d < (unsigned)N) atomicAdd(&deg[d], 1);
    }
}

// ---- 3-phase parallel exclusive scan of deg -> row_ptr (+ dinv/nself) ----

// phase A: per-block (1024-elem chunk) sums
__global__ __launch_bounds__(256) void k_bsum(const int* __restrict__ deg, int n,
                                              int* __restrict__ bsum) {
    int base = blockIdx.x * 1024;
    int local = 0;
#pragma unroll
    for (int j = 0; j < 4; ++j) {
        int idx = base + threadIdx.x + j * 256;
        if (idx < n) local += deg[idx];
    }
    __shared__ int s[4];
#pragma unroll
    for (int off = 32; off; off >>= 1) local += __shfl_down(local, off, 64);
    if ((threadIdx.x & 63) == 0) s[threadIdx.x >> 6] = local;
    __syncthreads();
    if (threadIdx.x == 0) bsum[blockIdx.x] = s[0] + s[1] + s[2] + s[3];
}

// phase B: single block exclusive scan of nb block sums (nb <= 256)
__global__ __launch_bounds__(256) void k_bscan(int* __restrict__ bsum, int nb) {
    __shared__ int s[256];
    int t = threadIdx.x;
    int v = (t < nb) ? bsum[t] : 0;
    s[t] = v;
    __syncthreads();
    for (int off = 1; off < 256; off <<= 1) {
        int u = (t >= off) ? s[t - off] : 0;
        __syncthreads();
        s[t] += u;
        __syncthreads();
    }
    if (t < nb) bsum[t] = s[t] - v;   // exclusive
}

// phase C: per-block local scan + block offset; write row_ptr, dinv, nself
__global__ __launch_bounds__(256) void k_rowptr(const int* __restrict__ deg,
                                                const int* __restrict__ boff, int n,
                                                int* __restrict__ row_ptr,
                                                float* __restrict__ dinv,
                                                float* __restrict__ nself) {
    __shared__ int s[256];
    int t = threadIdx.x;
    int base = blockIdx.x * 1024 + t * 4;
    int v0 = (base + 0 < n) ? deg[base + 0] : 0;
    int v1 = (base + 1 < n) ? deg[base + 1] : 0;
    int v2 = (base + 2 < n) ? deg[base + 2] : 0;
    int v3 = (base + 3 < n) ? deg[base + 3] : 0;
    int tot = v0 + v1 + v2 + v3;
    s[t] = tot;
    __syncthreads();
    for (int off = 1; off < 256; off <<= 1) {
        int u = (t >= off) ? s[t - off] : 0;
        __syncthreads();
        s[t] += u;
        __syncthreads();
    }
    int run = boff[blockIdx.x] + ((t == 0) ? 0 : s[t - 1]);
    int vals[4] = {v0, v1, v2, v3};
#pragma unroll
    for (int j = 0; j < 4; ++j) {
        int idx = base + j;
        if (idx < n) {
            row_ptr[idx] = run;
            run += vals[j];
            float df = (float)vals[j] + 1.0f;
            dinv[idx] = rsqrtf(df);
            nself[idx] = 1.0f / df;
        }
    }
    if (blockIdx.x == gridDim.x - 1 && t == 255) row_ptr[n] = boff[blockIdx.x] + s[255];
}

__global__ void k_fill(const int* __restrict__ ei, int E, int N,
                       const int* __restrict__ flags,
                       const int* __restrict__ row_ptr, int* __restrict__ cnt,
                       int* __restrict__ col) {
    int e = blockIdx.x * blockDim.x + threadIdx.x;
    if (e < E) {
        int is64 = flags[11];
        int s = is64 ? ei[2 * e] : ei[e];
        int d = is64 ? ei[2 * E + 2 * e] : ei[E + e];
        if ((unsigned)d < (unsigned)N) {
            int pos = row_ptr[d] + atomicAdd(&cnt[d], 1);
            col[pos] = ((unsigned)s < (unsigned)N) ? s : 0;
        }
    }
}

// transpose + canonicalize weights to bf16: W[K x F] -> WT[F x K]
__global__ void k_pack(const void* __restrict__ W1, const void* __restrict__ W2,
                       const void* __restrict__ W3, const void* __restrict__ Wr,
                       const void* __restrict__ Wl, const int* __restrict__ flags,
                       ushort_t* __restrict__ T1, ushort_t* __restrict__ T2,
                       ushort_t* __restrict__ T3, ushort_t* __restrict__ Tr,
                       ushort_t* __restrict__ Tl) {
    int i = blockIdx.x * blockDim.x + threadIdx.x;
    const int SQ = 128 * 128;
    if (i < 4 * SQ) {
        int m = i / SQ, r = i % SQ;
        int k = r / 128, f = r % 128;
        const void* W = (m == 0) ? W1 : (m == 1) ? W2 : (m == 2) ? W3 : Wr;
        ushort_t* T = (m == 0) ? T1 : (m == 1) ? T2 : (m == 2) ? T3 : Tr;
        int fid = (m == 0) ? 1 : (m == 1) ? 3 : (m == 2) ? 5 : 7;
        T[f * 128 + k] = f2bf(loadF(W, (size_t)k * 128 + f, flags[fid]));
    } else if (i < 4 * SQ + 128 * 64) {
        int r = i - 4 * SQ;
        int k = r / 64, f = r % 64;
        Tl[f * 128 + k] = f2bf(loadF(Wl, (size_t)k * 64 + f, flags[9]));
    }
}

// ---------------- GEMM: A[M x 128] @ W[128 x (NCT*16)] ----------------
template <int NCT>
__global__ __launch_bounds__(256) void k_gemm(const void* __restrict__ A, int aFid, int aFix,
                                              const ushort_t* __restrict__ WT,
                                              const void* __restrict__ bias, int bFid,
                                              void* __restrict__ C, int cFid, int cFix,
                                              int M, const int* __restrict__ flags) {
    const int K = 128;
    const int F = NCT * 16;
    int wave = threadIdx.x >> 6;
    int lane = threadIdx.x & 63;
    int quad = lane >> 4;
    int l16 = lane & 15;
    int rowBase = blockIdx.x * 64 + wave * 16;

    int a16 = (aFid >= 0) ? flags[aFid] : aFix;
    int c16 = (cFid >= 0) ? flags[cFid] : cFix;

    int arow = rowBase + l16;
    if (arow >= M) arow = M - 1;

    f32x4 acc[NCT];
#pragma unroll
    for (int c = 0; c < NCT; ++c) acc[c] = (f32x4){0.f, 0.f, 0.f, 0.f};

    const ushort_t* aptr16 = (const ushort_t*)A + (size_t)arow * K + quad * 8;
    const float*    aptr32 = (const float*)A + (size_t)arow * K + quad * 8;

#pragma unroll
    for (int kk = 0; kk < K; kk += 32) {
        bf16x8 a;
        if (a16) {
            a = *(const bf16x8*)(aptr16 + kk);
        } else {
            const f32x4* p = (const f32x4*)(aptr32 + kk);
            f32x4 u0 = p[0], u1 = p[1];
#pragma unroll
            for (int j = 0; j < 4; ++j) {
                BFU e0; e0.u = f2bf(u0[j]); a[j] = e0.h;
                BFU e1; e1.u = f2bf(u1[j]); a[j + 4] = e1.h;
            }
        }
#pragma unroll
        for (int c = 0; c < NCT; ++c) {
            const ushort_t* bp = WT + (size_t)(c * 16 + l16) * K + quad * 8 + kk;
            bf16x8 b = *(const bf16x8*)bp;
            acc[c] = __builtin_amdgcn_mfma_f32_16x16x32_bf16(a, b, acc[c], 0, 0, 0);
        }
    }

    int bf = (bias && bFid >= 0) ? flags[bFid] : 1;
#pragma unroll
    for (int c = 0; c < NCT; ++c) {
        int colg = c * 16 + l16;
        float bv = bias ? loadF(bias, colg, bf) : 0.0f;
#pragma unroll
        for (int r = 0; r < 4; ++r) {
            int row = rowBase + quad * 4 + r;
            if (row < M) {
                float v = acc[c][r] + bv;
                if (c16) ((ushort_t*)C)[(size_t)row * F + colg] = f2bf(v);
                else     ((float*)C)[(size_t)row * F + colg] = v;
            }
        }
    }
}

// ---------------- aggregation: one wave per node, lane owns 2 features ----------------
__global__ __launch_bounds__(256) void k_agg(const void* __restrict__ H, int h16,
                                             const int* __restrict__ row_ptr,
                                             const int* __restrict__ col,
                                             const float* __restrict__ dinv,
                                             const float* __restrict__ nself,
                                             const void* __restrict__ bias, int bFid,
                                             const void* __restrict__ other, int o16,
                                             void* __restrict__ Out, int out16,
                                             int n, const int* __restrict__ flags) {
    int node = (blockIdx.x * blockDim.x + threadIdx.x) >> 6;
    if (node >= n) return;
    int lane = threadIdx.x & 63;
    int f = lane * 2;

    float dn = dinv[node];
    float ns = nself[node];
    size_t nidx = (size_t)node * 128 + f;

    float a0, a1;
    if (h16) {
        uint_t hv = *(const uint_t*)((const ushort_t*)H + nidx);
        a0 = bf2f(hv & 0xffffu) * ns;
        a1 = bf2f(hv >> 16) * ns;
    } else {
        const float* p = (const float*)H + nidx;
        a0 = p[0] * ns;
        a1 = p[1] * ns;
    }

    int beg = row_ptr[node], end = row_ptr[node + 1];
    if (h16) {
        for (int i = beg; i < end; ++i) {
            int s = col[i];
            float w = dinv[s] * dn;
            uint_t v = *(const uint_t*)((const ushort_t*)H + (size_t)s * 128 + f);
            a0 = fmaf(bf2f(v & 0xffffu), w, a0);
            a1 = fmaf(bf2f(v >> 16), w, a1);
        }
    } else {
        for (int i = beg; i < end; ++i) {
            int s = col[i];
            float w = dinv[s] * dn;
            const float* p = (const float*)H + (size_t)s * 128 + f;
            a0 = fmaf(p[0], w, a0);
            a1 = fmaf(p[1], w, a1);
        }
    }

    int bfm = flags[bFid];
    a0 += loadF(bias, f, bfm);
    a1 += loadF(bias, f + 1, bfm);
    if (other) {
        a0 += loadF(other, nidx, o16);
        a1 += loadF(other, nidx + 1, o16);
    }
    a0 = fmaxf(a0, 0.0f);
    a1 = fmaxf(a1, 0.0f);
    if (out16) {
        uint_t outv = (uint_t)f2bf(a0) | ((uint_t)f2bf(a1) << 16);
        *(uint_t*)((ushort_t*)Out + nidx) = outv;
    } else {
        float* p = (float*)Out + nidx;
        p[0] = a0;
        p[1] = a1;
    }
}

// ---------------- launch ----------------

extern "C" void kernel_launch(void* const* d_in, const int* in_sizes, int n_in,
                              void* d_out, int out_size, void* d_ws, size_t ws_size,
                              hipStream_t stream) {
    const int N = in_sizes[0] / 128;
    const int E = in_sizes[1] / 2;

    const void* x  = d_in[0];
    const int*  ei = (const int*)d_in[1];

    char* ws = (char*)d_ws;
    size_t used = 0;
    auto alloc = [&](size_t bytes) {
        char* p = ws + used;
        used += (bytes + 255) & ~(size_t)255;
        return p;
    };

    int*   flags   = (int*)alloc(64 * 4);
    int*   deg     = (int*)alloc((size_t)2 * N * 4);
    int*   cnt     = deg + N;
    int*   row_ptr = (int*)alloc((size_t)(N + 1) * 4);
    float* dinv    = (float*)alloc((size_t)N * 4);
    float* nself   = (float*)alloc((size_t)N * 4);
    int*   colv    = (int*)alloc((size_t)E * 4);
    int*   bsum    = (int*)alloc(256 * 4);
    ushort_t* T1   = (ushort_t*)alloc(128 * 128 * 2);
    ushort_t* T2   = (ushort_t*)alloc(128 * 128 * 2);
    ushort_t* T3   = (ushort_t*)alloc(128 * 128 * 2);
    ushort_t* Tres = (ushort_t*)alloc(128 * 128 * 2);
    ushort_t* Tlin = (ushort_t*)alloc(128 * 64 * 2);

    // intermediates: fp32 if workspace allows, else bf16
    size_t remain = (ws_size > used) ? ws_size - used : 0;
    size_t needF32 = 3 * (((size_t)N * 128 * 4 + 255) & ~(size_t)255);
    int im = (remain >= needF32) ? 0 : 1;
    size_t esz = im ? 2 : 4;
    void* Hbuf = alloc((size_t)N * 128 * esz);
    void* O1   = alloc((size_t)N * 128 * esz);
    void* Xres = alloc((size_t)N * 128 * esz);

    if (used > ws_size) return;

    DetectArgs da;
    for (int i = 0; i < 11; ++i) { da.t[i] = d_in[i == 0 ? 0 : i + 1]; da.elems[i] = in_sizes[i == 0 ? 0 : i + 1]; }
    da.ei = ei;
    da.flags = flags;

    const int B = 256;
    int gZero = (2 * N + B - 1) / B;
    int gE    = (E + B - 1) / B;
    int gPack = (4 * 128 * 128 + 128 * 64 + B - 1) / B;
    int gGemm = (N + 63) / 64;
    int gAgg  = (N + 3) / 4;
    int nb    = (N + 1023) / 1024;   // scan chunks (<=256 for N<=262144)

    k_detect<<<1, 64, 0, stream>>>(da);
    k_zero<<<gZero, B, 0, stream>>>(deg, 2 * N);
    k_pack<<<gPack, B, 0, stream>>>(d_in[2], d_in[4], d_in[6], d_in[8], d_in[10], flags,
                                    T1, T2, T3, Tres, Tlin);
    k_deg<<<gE, B, 0, stream>>>(ei, E, N, flags, deg);
    k_bsum<<<nb, B, 0, stream>>>(deg, N, bsum);
    k_bscan<<<1, B, 0, stream>>>(bsum, nb);
    k_rowptr<<<nb, B, 0, stream>>>(deg, bsum, N, row_ptr, dinv, nself);
    k_fill<<<gE, B, 0, stream>>>(ei, E, N, flags, row_ptr, cnt, colv);

    // layer 1: H = x@W1 ; Xres = x@Wres + bres ; O1 = relu(agg(H) + b1 + Xres)
    k_gemm<8><<<gGemm, B, 0, stream>>>(x, 0, 0, T1, nullptr, -1, Hbuf, -1, im, N, flags);
    k_gemm<8><<<gGemm, B, 0, stream>>>(x, 0, 0, Tres, d_in[9], 8, Xres, -1, im, N, flags);
    k_agg<<<gAgg, B, 0, stream>>>(Hbuf, im, row_ptr, colv, dinv, nself, d_in[3], 2,
                                  Xres, im, O1, im, N, flags);

    // layer 2
    k_gemm<8><<<gGemm, B, 0, stream>>>(O1, -1, im, T2, nullptr, -1, Hbuf, -1, im, N, flags);
    k_agg<<<gAgg, B, 0, stream>>>(Hbuf, im, row_ptr, colv, dinv, nself, d_in[5], 4,
                                  nullptr, 0, Xres, im, N, flags);

    // layer 3
    k_gemm<8><<<gGemm, B, 0, stream>>>(Xres, -1, im, T3, nullptr, -1, Hbuf, -1, im, N, flags);
    k_agg<<<gAgg, B, 0, stream>>>(Hbuf, im, row_ptr, colv, dinv, nself, d_in[7], 6,
                                  nullptr, 0, O1, im, N, flags);

    // final: out = O3@Wlin + blin (fp32 out)
    k_gemm<4><<<gGemm, B, 0, stream>>>(O1, -1, im, Tlin, d_in[11], 10,
                                       d_out, 0, 0, N, flags);
}

// Round 5
// 504.031 us; speedup vs baseline: 1.3007x; 1.0352x over previous
//
#include <hip/hip_runtime.h>

typedef unsigned short ushort_t;
typedef unsigned int uint_t;

typedef __bf16 bf16x8 __attribute__((ext_vector_type(8)));
typedef float f32x4 __attribute__((ext_vector_type(4)));

union BFU { ushort_t u; __bf16 h; };

__device__ __forceinline__ float bf2f(uint_t u) {
    union { uint_t i; float f; } v; v.i = u << 16; return v.f;
}
__device__ __forceinline__ ushort_t f2bf(float f) {
    union { float f; uint_t i; } v; v.f = f;
    uint_t r = v.i + 0x7fffu + ((v.i >> 16) & 1u);
    return (ushort_t)(r >> 16);
}
// mode: 1 = bf16 storage, 0 = fp32 storage
__device__ __forceinline__ float loadF(const void* p, size_t i, int isBf16) {
    return isBf16 ? bf2f((uint_t)((const ushort_t*)p)[i]) : ((const float*)p)[i];
}

// ---------------- dtype detection ----------------
// flags[0..10]: x,W1,b1,W2,b2,W3,b3,Wres,bres,Wlin,blin  (1=bf16, 0=fp32)
// flags[11]: edge_index is int64 (1) or int32 (0)
struct DetectArgs {
    const void* t[11];
    int elems[11];
    const int* ei;
    int* flags;
};

__global__ void k_detect(DetectArgs a) {
    int t = threadIdx.x;
    if (t < 11) {
        const uint_t* w = (const uint_t*)a.t[t];
        int n = a.elems[t] / 2; if (n > 64) n = 64;
        int cnt = 0;
        for (int i = 0; i < n; ++i) {
            uint_t field = (w[i] >> 7) & 0xFFu;
            cnt += (field >= 100u && field <= 135u);
        }
        a.flags[t] = (cnt * 10 >= n * 6) ? 1 : 0;
    } else if (t == 11) {
        int nz = 0;
        for (int i = 0; i < 64; ++i) nz += (a.ei[2 * i + 1] != 0);
        a.flags[11] = (nz == 0) ? 1 : 0;
    }
}

// ---------------- preprocessing ----------------

__global__ void k_zero(int* p, int n) {
    int i = blockIdx.x * blockDim.x + threadIdx.x;
    if (i < n) p[i] = 0;
}

__global__ void k_deg(const int* __restrict__ ei, int E, int N,
                      const int* __restrict__ flags, int* __restrict__ deg) {
    int e = blockIdx.x * blockDim.x + threadIdx.x;
    if (e < E) {
        int is64 = flags[11];
        int d = is64 ? ei[2 * E + 2 * e] : ei[E + e];
        if ((unsigned)d < (unsigned)N) atomicAdd(&deg[d], 1);
    }
}

// ---- 3-phase parallel exclusive scan of deg -> row_ptr (+ dinv/nself) ----

__global__ __launch_bounds__(256) void k_bsum(const int* __restrict__ deg, int n,
                                              int* __restrict__ bsum) {
    int base = blockIdx.x * 1024;
    int local = 0;
#pragma unroll
    for (int j = 0; j < 4; ++j) {
        int idx = base + threadIdx.x + j * 256;
        if (idx < n) local += deg[idx];
    }
    __shared__ int s[4];
#pragma unroll
    for (int off = 32; off; off >>= 1) local += __shfl_down(local, off, 64);
    if ((threadIdx.x & 63) == 0) s[threadIdx.x >> 6] = local;
    __syncthreads();
    if (threadIdx.x == 0) bsum[blockIdx.x] = s[0] + s[1] + s[2] + s[3];
}

__global__ __launch_bounds__(256) void k_bscan(int* __restrict__ bsum, int nb) {
    __shared__ int s[256];
    int t = threadIdx.x;
    int v = (t < nb) ? bsum[t] : 0;
    s[t] = v;
    __syncthreads();
    for (int off = 1; off < 256; off <<= 1) {
        int u = (t >= off) ? s[t - off] : 0;
        __syncthreads();
        s[t] += u;
        __syncthreads();
    }
    if (t < nb) bsum[t] = s[t] - v;   // exclusive
}

__global__ __launch_bounds__(256) void k_rowptr(const int* __restrict__ deg,
                                                const int* __restrict__ boff, int n,
                                                int* __restrict__ row_ptr,
                                                float* __restrict__ dinv,
                                                float* __restrict__ nself) {
    __shared__ int s[256];
    int t = threadIdx.x;
    int base = blockIdx.x * 1024 + t * 4;
    int v0 = (base + 0 < n) ? deg[base + 0] : 0;
    int v1 = (base + 1 < n) ? deg[base + 1] : 0;
    int v2 = (base + 2 < n) ? deg[base + 2] : 0;
    int v3 = (base + 3 < n) ? deg[base + 3] : 0;
    int tot = v0 + v1 + v2 + v3;
    s[t] = tot;
    __syncthreads();
    for (int off = 1; off < 256; off <<= 1) {
        int u = (t >= off) ? s[t - off] : 0;
        __syncthreads();
        s[t] += u;
        __syncthreads();
    }
    int run = boff[blockIdx.x] + ((t == 0) ? 0 : s[t - 1]);
    int vals[4] = {v0, v1, v2, v3};
#pragma unroll
    for (int j = 0; j < 4; ++j) {
        int idx = base + j;
        if (idx < n) {
            row_ptr[idx] = run;
            run += vals[j];
            float df = (float)vals[j] + 1.0f;
            dinv[idx] = rsqrtf(df);
            nself[idx] = 1.0f / df;
        }
    }
    if (blockIdx.x == gridDim.x - 1 && t == 255) row_ptr[n] = boff[blockIdx.x] + s[255];
}

// fill CSR cols + precomputed edge weights w = dinv[src]*dinv[dst]
__global__ void k_fill(const int* __restrict__ ei, int E, int N,
                       const int* __restrict__ flags,
                       const int* __restrict__ row_ptr, int* __restrict__ cnt,
                       const float* __restrict__ dinv,
                       int* __restrict__ col, float* __restrict__ wgt) {
    int e = blockIdx.x * blockDim.x + threadIdx.x;
    if (e < E) {
        int is64 = flags[11];
        int s = is64 ? ei[2 * e] : ei[e];
        int d = is64 ? ei[2 * E + 2 * e] : ei[E + e];
        if ((unsigned)d < (unsigned)N) {
            int pos = row_ptr[d] + atomicAdd(&cnt[d], 1);
            int ss = ((unsigned)s < (unsigned)N) ? s : 0;
            col[pos] = ss;
            wgt[pos] = dinv[ss] * dinv[d];
        }
    }
}

// transpose + canonicalize weights to bf16: W[K x F] -> WT[F x K]
__global__ void k_pack(const void* __restrict__ W1, const void* __restrict__ W2,
                       const void* __restrict__ W3, const void* __restrict__ Wr,
                       const void* __restrict__ Wl, const int* __restrict__ flags,
                       ushort_t* __restrict__ T1, ushort_t* __restrict__ T2,
                       ushort_t* __restrict__ T3, ushort_t* __restrict__ Tr,
                       ushort_t* __restrict__ Tl) {
    int i = blockIdx.x * blockDim.x + threadIdx.x;
    const int SQ = 128 * 128;
    if (i < 4 * SQ) {
        int m = i / SQ, r = i % SQ;
        int k = r / 128, f = r % 128;
        const void* W = (m == 0) ? W1 : (m == 1) ? W2 : (m == 2) ? W3 : Wr;
        ushort_t* T = (m == 0) ? T1 : (m == 1) ? T2 : (m == 2) ? T3 : Tr;
        int fid = (m == 0) ? 1 : (m == 1) ? 3 : (m == 2) ? 5 : 7;
        T[f * 128 + k] = f2bf(loadF(W, (size_t)k * 128 + f, flags[fid]));
    } else if (i < 4 * SQ + 128 * 64) {
        int r = i - 4 * SQ;
        int k = r / 64, f = r % 64;
        Tl[f * 128 + k] = f2bf(loadF(Wl, (size_t)k * 64 + f, flags[9]));
    }
}

// ---------------- GEMM: A[M x 128] @ W[128 x (NCT*16)] ----------------
template <int NCT>
__global__ __launch_bounds__(256) void k_gemm(const void* __restrict__ A, int aFid, int aFix,
                                              const ushort_t* __restrict__ WT,
                                              const void* __restrict__ bias, int bFid,
                                              void* __restrict__ C, int cFix,
                                              int M, const int* __restrict__ flags) {
    const int K = 128;
    const int F = NCT * 16;
    int wave = threadIdx.x >> 6;
    int lane = threadIdx.x & 63;
    int quad = lane >> 4;
    int l16 = lane & 15;
    int rowBase = blockIdx.x * 64 + wave * 16;

    int a16 = (aFid >= 0) ? flags[aFid] : aFix;
    int c16 = cFix;

    int arow = rowBase + l16;
    if (arow >= M) arow = M - 1;

    f32x4 acc[NCT];
#pragma unroll
    for (int c = 0; c < NCT; ++c) acc[c] = (f32x4){0.f, 0.f, 0.f, 0.f};

    const ushort_t* aptr16 = (const ushort_t*)A + (size_t)arow * K + quad * 8;
    const float*    aptr32 = (const float*)A + (size_t)arow * K + quad * 8;

#pragma unroll
    for (int kk = 0; kk < K; kk += 32) {
        bf16x8 a;
        if (a16) {
            a = *(const bf16x8*)(aptr16 + kk);
        } else {
            const f32x4* p = (const f32x4*)(aptr32 + kk);
            f32x4 u0 = p[0], u1 = p[1];
#pragma unroll
            for (int j = 0; j < 4; ++j) {
                BFU e0; e0.u = f2bf(u0[j]); a[j] = e0.h;
                BFU e1; e1.u = f2bf(u1[j]); a[j + 4] = e1.h;
            }
        }
#pragma unroll
        for (int c = 0; c < NCT; ++c) {
            const ushort_t* bp = WT + (size_t)(c * 16 + l16) * K + quad * 8 + kk;
            bf16x8 b = *(const bf16x8*)bp;
            acc[c] = __builtin_amdgcn_mfma_f32_16x16x32_bf16(a, b, acc[c], 0, 0, 0);
        }
    }

    int bf = (bias && bFid >= 0) ? flags[bFid] : 1;
#pragma unroll
    for (int c = 0; c < NCT; ++c) {
        int colg = c * 16 + l16;
        float bv = bias ? loadF(bias, colg, bf) : 0.0f;
#pragma unroll
        for (int r = 0; r < 4; ++r) {
            int row = rowBase + quad * 4 + r;
            if (row < M) {
                float v = acc[c][r] + bv;
                if (c16) ((ushort_t*)C)[(size_t)row * F + colg] = f2bf(v);
                else     ((float*)C)[(size_t)row * F + colg] = v;
            }
        }
    }
}

// ---------------- aggregation: one wave per node, lane owns 2 bf16 features ----------------
// H bf16 [n x 128]; precomputed edge weights; bias flag-dtyped; other fp32; Out bf16.
__global__ __launch_bounds__(256) void k_agg(const ushort_t* __restrict__ H,
                                             const int* __restrict__ row_ptr,
                                             const int* __restrict__ col,
                                             const float* __restrict__ wgt,
                                             const float* __restrict__ nself,
                                             const void* __restrict__ bias, int bFid,
                                             const float* __restrict__ other,
                                             ushort_t* __restrict__ Out,
                                             int n, const int* __restrict__ flags) {
    int node = (blockIdx.x * blockDim.x + threadIdx.x) >> 6;
    if (node >= n) return;
    int lane = threadIdx.x & 63;
    int f = lane * 2;

    float ns = nself[node];
    size_t nidx = (size_t)node * 128 + f;

    uint_t hv = *(const uint_t*)(H + nidx);
    float a0 = bf2f(hv & 0xffffu) * ns;
    float a1 = bf2f(hv >> 16) * ns;

    int beg = row_ptr[node], end = row_ptr[node + 1];
    for (int i = beg; i < end; ++i) {
        int s = col[i];
        float w = wgt[i];
        uint_t v = *(const uint_t*)(H + (size_t)s * 128 + f);
        a0 = fmaf(bf2f(v & 0xffffu), w, a0);
        a1 = fmaf(bf2f(v >> 16), w, a1);
    }

    int bfm = flags[bFid];
    a0 += loadF(bias, f, bfm);
    a1 += loadF(bias, f + 1, bfm);
    if (other) {
        a0 += other[nidx];
        a1 += other[nidx + 1];
    }
    a0 = fmaxf(a0, 0.0f);
    a1 = fmaxf(a1, 0.0f);
    uint_t outv = (uint_t)f2bf(a0) | ((uint_t)f2bf(a1) << 16);
    *(uint_t*)(Out + nidx) = outv;
}

// ---------------- launch ----------------

extern "C" void kernel_launch(void* const* d_in, const int* in_sizes, int n_in,
                              void* d_out, int out_size, void* d_ws, size_t ws_size,
                              hipStream_t stream) {
    const int N = in_sizes[0] / 128;
    const int E = in_sizes[1] / 2;

    const void* x  = d_in[0];
    const int*  ei = (const int*)d_in[1];

    char* ws = (char*)d_ws;
    size_t used = 0;
    auto alloc = [&](size_t bytes) {
        char* p = ws + used;
        used += (bytes + 255) & ~(size_t)255;
        return p;
    };

    int*   flags   = (int*)alloc(64 * 4);
    int*   deg     = (int*)alloc((size_t)2 * N * 4);
    int*   cnt     = deg + N;
    int*   row_ptr = (int*)alloc((size_t)(N + 1) * 4);
    float* dinv    = (float*)alloc((size_t)N * 4);
    float* nself   = (float*)alloc((size_t)N * 4);
    int*   colv    = (int*)alloc((size_t)E * 4);
    float* wgt     = (float*)alloc((size_t)E * 4);
    int*   bsum    = (int*)alloc(256 * 4);
    ushort_t* T1   = (ushort_t*)alloc(128 * 128 * 2);
    ushort_t* T2   = (ushort_t*)alloc(128 * 128 * 2);
    ushort_t* T3   = (ushort_t*)alloc(128 * 128 * 2);
    ushort_t* Tres = (ushort_t*)alloc(128 * 128 * 2);
    ushort_t* Tlin = (ushort_t*)alloc(128 * 64 * 2);

    ushort_t* Hbuf = (ushort_t*)alloc((size_t)N * 128 * 2);  // gather source, bf16
    ushort_t* Act1 = (ushort_t*)alloc((size_t)N * 128 * 2);  // activations, bf16
    ushort_t* Act2 = (ushort_t*)alloc((size_t)N * 128 * 2);
    float*    Xres = (float*)alloc((size_t)N * 128 * 4);     // residual, fp32

    if (used > ws_size) return;

    DetectArgs da;
    for (int i = 0; i < 11; ++i) { da.t[i] = d_in[i == 0 ? 0 : i + 1]; da.elems[i] = in_sizes[i == 0 ? 0 : i + 1]; }
    da.ei = ei;
    da.flags = flags;

    const int B = 256;
    int gZero = (2 * N + B - 1) / B;
    int gE    = (E + B - 1) / B;
    int gPack = (4 * 128 * 128 + 128 * 64 + B - 1) / B;
    int gGemm = (N + 63) / 64;
    int gAgg  = (N + 3) / 4;
    int nb    = (N + 1023) / 1024;

    k_detect<<<1, 64, 0, stream>>>(da);
    k_zero<<<gZero, B, 0, stream>>>(deg, 2 * N);
    k_pack<<<gPack, B, 0, stream>>>(d_in[2], d_in[4], d_in[6], d_in[8], d_in[10], flags,
                                    T1, T2, T3, Tres, Tlin);
    k_deg<<<gE, B, 0, stream>>>(ei, E, N, flags, deg);
    k_bsum<<<nb, B, 0, stream>>>(deg, N, bsum);
    k_bscan<<<1, B, 0, stream>>>(bsum, nb);
    k_rowptr<<<nb, B, 0, stream>>>(deg, bsum, N, row_ptr, dinv, nself);
    k_fill<<<gE, B, 0, stream>>>(ei, E, N, flags, row_ptr, cnt, dinv, colv, wgt);

    // layer 1: H = x@W1 (bf16) ; Xres = x@Wres + bres (fp32) ; Act1 = relu(agg + b1 + Xres)
    k_gemm<8><<<gGemm, B, 0, stream>>>(x, 0, 0, T1, nullptr, -1, Hbuf, 1, N, flags);
    k_gemm<8><<<gGemm, B, 0, stream>>>(x, 0, 0, Tres, d_in[9], 8, Xres, 0, N, flags);
    k_agg<<<gAgg, B, 0, stream>>>(Hbuf, row_ptr, colv, wgt, nself, d_in[3], 2,
                                  Xres, Act1, N, flags);

    // layer 2: H = Act1@W2 ; Act2 = relu(agg + b2)
    k_gemm<8><<<gGemm, B, 0, stream>>>(Act1, -1, 1, T2, nullptr, -1, Hbuf, 1, N, flags);
    k_agg<<<gAgg, B, 0, stream>>>(Hbuf, row_ptr, colv, wgt, nself, d_in[5], 4,
                                  nullptr, Act2, N, flags);

    // layer 3: H = Act2@W3 ; Act1 = relu(agg + b3)   (reuse Act1)
    k_gemm<8><<<gGemm, B, 0, stream>>>(Act2, -1, 1, T3, nullptr, -1, Hbuf, 1, N, flags);
    k_agg<<<gAgg, B, 0, stream>>>(Hbuf, row_ptr, colv, wgt, nself, d_in[7], 6,
                                  nullptr, Act1, N, flags);

    // final: out = Act1@Wlin + blin (fp32 out)
    k_gemm<4><<<gGemm, B, 0, stream>>>(Act1, -1, 1, Tlin, d_in[11], 10,
                                       d_out, 0, N, flags);
}

// Round 6
// 384.864 us; speedup vs baseline: 1.7034x; 1.3096x over previous
//
#include <hip/hip_runtime.h>

typedef unsigned short ushort_t;
typedef unsigned int uint_t;

typedef __bf16 bf16x8 __attribute__((ext_vector_type(8)));
typedef float f32x4 __attribute__((ext_vector_type(4)));

union BFU { ushort_t u; __bf16 h; };

__device__ __forceinline__ float bf2f(uint_t u) {
    union { uint_t i; float f; } v; v.i = u << 16; return v.f;
}
__device__ __forceinline__ ushort_t f2bf(float f) {
    union { float f; uint_t i; } v; v.f = f;
    uint_t r = v.i + 0x7fffu + ((v.i >> 16) & 1u);
    return (ushort_t)(r >> 16);
}
// mode: 1 = bf16 storage, 0 = fp32 storage
__device__ __forceinline__ float loadF(const void* p, size_t i, int isBf16) {
    return isBf16 ? bf2f((uint_t)((const ushort_t*)p)[i]) : ((const float*)p)[i];
}

// ---------------- dtype detection ----------------
// flags[0..10]: x,W1,b1,W2,b2,W3,b3,Wres,bres,Wlin,blin  (1=bf16, 0=fp32)
// flags[11]: edge_index is int64 (1) or int32 (0)
struct DetectArgs {
    const void* t[11];
    int elems[11];
    const int* ei;
    int* flags;
};

__global__ void k_detect(DetectArgs a) {
    int t = threadIdx.x;
    if (t < 11) {
        const uint_t* w = (const uint_t*)a.t[t];
        int n = a.elems[t] / 2; if (n > 64) n = 64;
        int cnt = 0;
        for (int i = 0; i < n; ++i) {
            uint_t field = (w[i] >> 7) & 0xFFu;
            cnt += (field >= 100u && field <= 135u);
        }
        a.flags[t] = (cnt * 10 >= n * 6) ? 1 : 0;
    } else if (t == 11) {
        int nz = 0;
        for (int i = 0; i < 64; ++i) nz += (a.ei[2 * i + 1] != 0);
        a.flags[11] = (nz == 0) ? 1 : 0;
    }
}

// ---------------- preprocessing ----------------

__global__ void k_zero(int* p, int n) {
    int i = blockIdx.x * blockDim.x + threadIdx.x;
    if (i < n) p[i] = 0;
}

__global__ void k_deg(const int* __restrict__ ei, int E, int N,
                      const int* __restrict__ flags, int* __restrict__ deg) {
    int e = blockIdx.x * blockDim.x + threadIdx.x;
    if (e < E) {
        int is64 = flags[11];
        int d = is64 ? ei[2 * E + 2 * e] : ei[E + e];
        if ((unsigned)d < (unsigned)N) atomicAdd(&deg[d], 1);
    }
}

// ---- 3-phase parallel exclusive scan of deg -> row_ptr (+ dinv/nself) ----

__global__ __launch_bounds__(256) void k_bsum(const int* __restrict__ deg, int n,
                                              int* __restrict__ bsum) {
    int base = blockIdx.x * 1024;
    int local = 0;
#pragma unroll
    for (int j = 0; j < 4; ++j) {
        int idx = base + threadIdx.x + j * 256;
        if (idx < n) local += deg[idx];
    }
    __shared__ int s[4];
#pragma unroll
    for (int off = 32; off; off >>= 1) local += __shfl_down(local, off, 64);
    if ((threadIdx.x & 63) == 0) s[threadIdx.x >> 6] = local;
    __syncthreads();
    if (threadIdx.x == 0) bsum[blockIdx.x] = s[0] + s[1] + s[2] + s[3];
}

__global__ __launch_bounds__(256) void k_bscan(int* __restrict__ bsum, int nb) {
    __shared__ int s[256];
    int t = threadIdx.x;
    int v = (t < nb) ? bsum[t] : 0;
    s[t] = v;
    __syncthreads();
    for (int off = 1; off < 256; off <<= 1) {
        int u = (t >= off) ? s[t - off] : 0;
        __syncthreads();
        s[t] += u;
        __syncthreads();
    }
    if (t < nb) bsum[t] = s[t] - v;   // exclusive
}

__global__ __launch_bounds__(256) void k_rowptr(const int* __restrict__ deg,
                                                const int* __restrict__ boff, int n,
                                                int* __restrict__ row_ptr,
                                                float* __restrict__ dinv,
                                                float* __restrict__ nself) {
    __shared__ int s[256];
    int t = threadIdx.x;
    int base = blockIdx.x * 1024 + t * 4;
    int v0 = (base + 0 < n) ? deg[base + 0] : 0;
    int v1 = (base + 1 < n) ? deg[base + 1] : 0;
    int v2 = (base + 2 < n) ? deg[base + 2] : 0;
    int v3 = (base + 3 < n) ? deg[base + 3] : 0;
    int tot = v0 + v1 + v2 + v3;
    s[t] = tot;
    __syncthreads();
    for (int off = 1; off < 256; off <<= 1) {
        int u = (t >= off) ? s[t - off] : 0;
        __syncthreads();
        s[t] += u;
        __syncthreads();
    }
    int run = boff[blockIdx.x] + ((t == 0) ? 0 : s[t - 1]);
    int vals[4] = {v0, v1, v2, v3};
#pragma unroll
    for (int j = 0; j < 4; ++j) {
        int idx = base + j;
        if (idx < n) {
            row_ptr[idx] = run;
            run += vals[j];
            float df = (float)vals[j] + 1.0f;
            dinv[idx] = rsqrtf(df);
            nself[idx] = 1.0f / df;
        }
    }
    if (blockIdx.x == gridDim.x - 1 && t == 255) row_ptr[n] = boff[blockIdx.x] + s[255];
}

// fill CSR cols + precomputed edge weights w = dinv[src]*dinv[dst]
__global__ void k_fill(const int* __restrict__ ei, int E, int N,
                       const int* __restrict__ flags,
                       const int* __restrict__ row_ptr, int* __restrict__ cnt,
                       const float* __restrict__ dinv,
                       int* __restrict__ col, float* __restrict__ wgt) {
    int e = blockIdx.x * blockDim.x + threadIdx.x;
    if (e < E) {
        int is64 = flags[11];
        int s = is64 ? ei[2 * e] : ei[e];
        int d = is64 ? ei[2 * E + 2 * e] : ei[E + e];
        if ((unsigned)d < (unsigned)N) {
            int pos = row_ptr[d] + atomicAdd(&cnt[d], 1);
            int ss = ((unsigned)s < (unsigned)N) ? s : 0;
            col[pos] = ss;
            wgt[pos] = dinv[ss] * dinv[d];
        }
    }
}

// transpose + canonicalize weights to bf16: W[K x F] -> WT[F x K]
__global__ void k_pack(const void* __restrict__ W1, const void* __restrict__ W2,
                       const void* __restrict__ W3, const void* __restrict__ Wr,
                       const void* __restrict__ Wl, const int* __restrict__ flags,
                       ushort_t* __restrict__ T1, ushort_t* __restrict__ T2,
                       ushort_t* __restrict__ T3, ushort_t* __restrict__ Tr,
                       ushort_t* __restrict__ Tl) {
    int i = blockIdx.x * blockDim.x + threadIdx.x;
    const int SQ = 128 * 128;
    if (i < 4 * SQ) {
        int m = i / SQ, r = i % SQ;
        int k = r / 128, f = r % 128;
        const void* W = (m == 0) ? W1 : (m == 1) ? W2 : (m == 2) ? W3 : Wr;
        ushort_t* T = (m == 0) ? T1 : (m == 1) ? T2 : (m == 2) ? T3 : Tr;
        int fid = (m == 0) ? 1 : (m == 1) ? 3 : (m == 2) ? 5 : 7;
        T[f * 128 + k] = f2bf(loadF(W, (size_t)k * 128 + f, flags[fid]));
    } else if (i < 4 * SQ + 128 * 64) {
        int r = i - 4 * SQ;
        int k = r / 64, f = r % 64;
        Tl[f * 128 + k] = f2bf(loadF(Wl, (size_t)k * 64 + f, flags[9]));
    }
}

// ---------------- GEMM: A[M x 128] @ W[128 x (NCT*16)] ----------------
template <int NCT>
__global__ __launch_bounds__(256) void k_gemm(const void* __restrict__ A, int aFid, int aFix,
                                              const ushort_t* __restrict__ WT,
                                              const void* __restrict__ bias, int bFid,
                                              void* __restrict__ C, int cFix,
                                              int M, const int* __restrict__ flags) {
    const int K = 128;
    const int F = NCT * 16;
    int wave = threadIdx.x >> 6;
    int lane = threadIdx.x & 63;
    int quad = lane >> 4;
    int l16 = lane & 15;
    int rowBase = blockIdx.x * 64 + wave * 16;

    int a16 = (aFid >= 0) ? flags[aFid] : aFix;
    int c16 = cFix;

    int arow = rowBase + l16;
    if (arow >= M) arow = M - 1;

    f32x4 acc[NCT];
#pragma unroll
    for (int c = 0; c < NCT; ++c) acc[c] = (f32x4){0.f, 0.f, 0.f, 0.f};

    const ushort_t* aptr16 = (const ushort_t*)A + (size_t)arow * K + quad * 8;
    const float*    aptr32 = (const float*)A + (size_t)arow * K + quad * 8;

#pragma unroll
    for (int kk = 0; kk < K; kk += 32) {
        bf16x8 a;
        if (a16) {
            a = *(const bf16x8*)(aptr16 + kk);
        } else {
            const f32x4* p = (const f32x4*)(aptr32 + kk);
            f32x4 u0 = p[0], u1 = p[1];
#pragma unroll
            for (int j = 0; j < 4; ++j) {
                BFU e0; e0.u = f2bf(u0[j]); a[j] = e0.h;
                BFU e1; e1.u = f2bf(u1[j]); a[j + 4] = e1.h;
            }
        }
#pragma unroll
        for (int c = 0; c < NCT; ++c) {
            const ushort_t* bp = WT + (size_t)(c * 16 + l16) * K + quad * 8 + kk;
            bf16x8 b = *(const bf16x8*)bp;
            acc[c] = __builtin_amdgcn_mfma_f32_16x16x32_bf16(a, b, acc[c], 0, 0, 0);
        }
    }

    int bf = (bias && bFid >= 0) ? flags[bFid] : 1;
#pragma unroll
    for (int c = 0; c < NCT; ++c) {
        int colg = c * 16 + l16;
        float bv = bias ? loadF(bias, colg, bf) : 0.0f;
#pragma unroll
        for (int r = 0; r < 4; ++r) {
            int row = rowBase + quad * 4 + r;
            if (row < M) {
                float v = acc[c][r] + bv;
                if (c16) ((ushort_t*)C)[(size_t)row * F + colg] = f2bf(v);
                else     ((float*)C)[(size_t)row * F + colg] = v;
            }
        }
    }
}

// ---------------- aggregation: one wave per node, batched-MLP gather ----------------
// H bf16 [n x 128]; precomputed edge weights; bias flag-dtyped; other fp32; Out bf16.
// Edge metadata (col/wgt) is preloaded 64-wide per wave and broadcast via shfl so the
// H-row gathers are address-independent and issue back-to-back (4x unrolled).
__global__ __launch_bounds__(256) void k_agg(const ushort_t* __restrict__ H,
                                             const int* __restrict__ row_ptr,
                                             const int* __restrict__ col,
                                             const float* __restrict__ wgt,
                                             const float* __restrict__ nself,
                                             const void* __restrict__ bias, int bFid,
                                             const float* __restrict__ other,
                                             ushort_t* __restrict__ Out,
                                             int n, const int* __restrict__ flags) {
    int node = (blockIdx.x * blockDim.x + threadIdx.x) >> 6;
    if (node >= n) return;
    int lane = threadIdx.x & 63;
    int f = lane * 2;

    float ns = nself[node];
    size_t nidx = (size_t)node * 128 + f;

    uint_t hv = *(const uint_t*)(H + nidx);
    float a0 = bf2f(hv & 0xffffu) * ns;
    float a1 = bf2f(hv >> 16) * ns;

    int beg = row_ptr[node], end = row_ptr[node + 1];
    for (int bs = beg; bs < end; bs += 64) {
        int rem = end - bs;
        int nb = (rem < 64) ? rem : 64;
        int me = bs + lane;
        int c = (lane < nb) ? col[me] : 0;
        float w = (lane < nb) ? wgt[me] : 0.0f;

        int j = 0;
        for (; j + 4 <= nb; j += 4) {
            int s0 = __shfl(c, j, 64), s1 = __shfl(c, j + 1, 64);
            int s2 = __shfl(c, j + 2, 64), s3 = __shfl(c, j + 3, 64);
            float w0 = __shfl(w, j, 64), w1 = __shfl(w, j + 1, 64);
            float w2 = __shfl(w, j + 2, 64), w3 = __shfl(w, j + 3, 64);
            uint_t v0 = *(const uint_t*)(H + (size_t)s0 * 128 + f);
            uint_t v1 = *(const uint_t*)(H + (size_t)s1 * 128 + f);
            uint_t v2 = *(const uint_t*)(H + (size_t)s2 * 128 + f);
            uint_t v3 = *(const uint_t*)(H + (size_t)s3 * 128 + f);
            a0 = fmaf(bf2f(v0 & 0xffffu), w0, a0);
            a1 = fmaf(bf2f(v0 >> 16), w0, a1);
            a0 = fmaf(bf2f(v1 & 0xffffu), w1, a0);
            a1 = fmaf(bf2f(v1 >> 16), w1, a1);
            a0 = fmaf(bf2f(v2 & 0xffffu), w2, a0);
            a1 = fmaf(bf2f(v2 >> 16), w2, a1);
            a0 = fmaf(bf2f(v3 & 0xffffu), w3, a0);
            a1 = fmaf(bf2f(v3 >> 16), w3, a1);
        }
        for (; j < nb; ++j) {
            int sj = __shfl(c, j, 64);
            float wj = __shfl(w, j, 64);
            uint_t v = *(const uint_t*)(H + (size_t)sj * 128 + f);
            a0 = fmaf(bf2f(v & 0xffffu), wj, a0);
            a1 = fmaf(bf2f(v >> 16), wj, a1);
        }
    }

    int bfm = flags[bFid];
    a0 += loadF(bias, f, bfm);
    a1 += loadF(bias, f + 1, bfm);
    if (other) {
        a0 += other[nidx];
        a1 += other[nidx + 1];
    }
    a0 = fmaxf(a0, 0.0f);
    a1 = fmaxf(a1, 0.0f);
    uint_t outv = (uint_t)f2bf(a0) | ((uint_t)f2bf(a1) << 16);
    *(uint_t*)(Out + nidx) = outv;
}

// ---------------- launch ----------------

extern "C" void kernel_launch(void* const* d_in, const int* in_sizes, int n_in,
                              void* d_out, int out_size, void* d_ws, size_t ws_size,
                              hipStream_t stream) {
    const int N = in_sizes[0] / 128;
    const int E = in_sizes[1] / 2;

    const void* x  = d_in[0];
    const int*  ei = (const int*)d_in[1];

    char* ws = (char*)d_ws;
    size_t used = 0;
    auto alloc = [&](size_t bytes) {
        char* p = ws + used;
        used += (bytes + 255) & ~(size_t)255;
        return p;
    };

    int*   flags   = (int*)alloc(64 * 4);
    int*   deg     = (int*)alloc((size_t)2 * N * 4);
    int*   cnt     = deg + N;
    int*   row_ptr = (int*)alloc((size_t)(N + 1) * 4);
    float* dinv    = (float*)alloc((size_t)N * 4);
    float* nself   = (float*)alloc((size_t)N * 4);
    int*   colv    = (int*)alloc((size_t)E * 4);
    float* wgt     = (float*)alloc((size_t)E * 4);
    int*   bsum    = (int*)alloc(256 * 4);
    ushort_t* T1   = (ushort_t*)alloc(128 * 128 * 2);
    ushort_t* T2   = (ushort_t*)alloc(128 * 128 * 2);
    ushort_t* T3   = (ushort_t*)alloc(128 * 128 * 2);
    ushort_t* Tres = (ushort_t*)alloc(128 * 128 * 2);
    ushort_t* Tlin = (ushort_t*)alloc(128 * 64 * 2);

    ushort_t* Hbuf = (ushort_t*)alloc((size_t)N * 128 * 2);  // gather source, bf16
    ushort_t* Act1 = (ushort_t*)alloc((size_t)N * 128 * 2);  // activations, bf16
    ushort_t* Act2 = (ushort_t*)alloc((size_t)N * 128 * 2);
    float*    Xres = (float*)alloc((size_t)N * 128 * 4);     // residual, fp32

    if (used > ws_size) return;

    DetectArgs da;
    for (int i = 0; i < 11; ++i) { da.t[i] = d_in[i == 0 ? 0 : i + 1]; da.elems[i] = in_sizes[i == 0 ? 0 : i + 1]; }
    da.ei = ei;
    da.flags = flags;

    const int B = 256;
    int gZero = (2 * N + B - 1) / B;
    int gE    = (E + B - 1) / B;
    int gPack = (4 * 128 * 128 + 128 * 64 + B - 1) / B;
    int gGemm = (N + 63) / 64;
    int gAgg  = (N + 3) / 4;
    int nb    = (N + 1023) / 1024;

    k_detect<<<1, 64, 0, stream>>>(da);
    k_zero<<<gZero, B, 0, stream>>>(deg, 2 * N);
    k_pack<<<gPack, B, 0, stream>>>(d_in[2], d_in[4], d_in[6], d_in[8], d_in[10], flags,
                                    T1, T2, T3, Tres, Tlin);
    k_deg<<<gE, B, 0, stream>>>(ei, E, N, flags, deg);
    k_bsum<<<nb, B, 0, stream>>>(deg, N, bsum);
    k_bscan<<<1, B, 0, stream>>>(bsum, nb);
    k_rowptr<<<nb, B, 0, stream>>>(deg, bsum, N, row_ptr, dinv, nself);
    k_fill<<<gE, B, 0, stream>>>(ei, E, N, flags, row_ptr, cnt, dinv, colv, wgt);

    // layer 1: H = x@W1 (bf16) ; Xres = x@Wres + bres (fp32) ; Act1 = relu(agg + b1 + Xres)
    k_gemm<8><<<gGemm, B, 0, stream>>>(x, 0, 0, T1, nullptr, -1, Hbuf, 1, N, flags);
    k_gemm<8><<<gGemm, B, 0, stream>>>(x, 0, 0, Tres, d_in[9], 8, Xres, 0, N, flags);
    k_agg<<<gAgg, B, 0, stream>>>(Hbuf, row_ptr, colv, wgt, nself, d_in[3], 2,
                                  Xres, Act1, N, flags);

    // layer 2: H = Act1@W2 ; Act2 = relu(agg + b2)
    k_gemm<8><<<gGemm, B, 0, stream>>>(Act1, -1, 1, T2, nullptr, -1, Hbuf, 1, N, flags);
    k_agg<<<gAgg, B, 0, stream>>>(Hbuf, row_ptr, colv, wgt, nself, d_in[5], 4,
                                  nullptr, Act2, N, flags);

    // layer 3: H = Act2@W3 ; Act1 = relu(agg + b3)   (reuse Act1)
    k_gemm<8><<<gGemm, B, 0, stream>>>(Act2, -1, 1, T3, nullptr, -1, Hbuf, 1, N, flags);
    k_agg<<<gAgg, B, 0, stream>>>(Hbuf, row_ptr, colv, wgt, nself, d_in[7], 6,
                                  nullptr, Act1, N, flags);

    // final: out = Act1@Wlin + blin (fp32 out)
    k_gemm<4><<<gGemm, B, 0, stream>>>(Act1, -1, 1, Tlin, d_in[11], 10,
                                       d_out, 0, N, flags);
}

// Round 7
// 375.842 us; speedup vs baseline: 1.7443x; 1.0240x over previous
//
#include <hip/hip_runtime.h>

typedef unsigned short ushort_t;
typedef unsigned int uint_t;

typedef __bf16 bf16x8 __attribute__((ext_vector_type(8)));
typedef float f32x4 __attribute__((ext_vector_type(4)));

union BFU { ushort_t u; __bf16 h; };

__device__ __forceinline__ float bf2f(uint_t u) {
    union { uint_t i; float f; } v; v.i = u << 16; return v.f;
}
__device__ __forceinline__ ushort_t f2bf(float f) {
    union { float f; uint_t i; } v; v.f = f;
    uint_t r = v.i + 0x7fffu + ((v.i >> 16) & 1u);
    return (ushort_t)(r >> 16);
}
// mode: 1 = bf16 storage, 0 = fp32 storage
__device__ __forceinline__ float loadF(const void* p, size_t i, int isBf16) {
    return isBf16 ? bf2f((uint_t)((const ushort_t*)p)[i]) : ((const float*)p)[i];
}

// ---------------- dtype detection ----------------
// flags[0..10]: x,W1,b1,W2,b2,W3,b3,Wres,bres,Wlin,blin  (1=bf16, 0=fp32)
// flags[11]: edge_index is int64 (1) or int32 (0)
struct DetectArgs {
    const void* t[11];
    int elems[11];
    const int* ei;
    int* flags;
};

__global__ void k_detect(DetectArgs a) {
    int t = threadIdx.x;
    if (t < 11) {
        const uint_t* w = (const uint_t*)a.t[t];
        int n = a.elems[t] / 2; if (n > 64) n = 64;
        int cnt = 0;
        for (int i = 0; i < n; ++i) {
            uint_t field = (w[i] >> 7) & 0xFFu;
            cnt += (field >= 100u && field <= 135u);
        }
        a.flags[t] = (cnt * 10 >= n * 6) ? 1 : 0;
    } else if (t == 11) {
        int nz = 0;
        for (int i = 0; i < 64; ++i) nz += (a.ei[2 * i + 1] != 0);
        a.flags[11] = (nz == 0) ? 1 : 0;
    }
}

// ---------------- preprocessing ----------------

__global__ void k_zero(int* p, int n) {
    int i = blockIdx.x * blockDim.x + threadIdx.x;
    if (i < n) p[i] = 0;
}

__global__ void k_deg(const int* __restrict__ ei, int E, int N,
                      const int* __restrict__ flags, int* __restrict__ deg) {
    int e = blockIdx.x * blockDim.x + threadIdx.x;
    if (e < E) {
        int is64 = flags[11];
        int d = is64 ? ei[2 * E + 2 * e] : ei[E + e];
        if ((unsigned)d < (unsigned)N) atomicAdd(&deg[d], 1);
    }
}

// ---- 3-phase parallel exclusive scan of deg -> row_ptr (+ dinv/nself/cnt) ----

__global__ __launch_bounds__(256) void k_bsum(const int* __restrict__ deg, int n,
                                              int* __restrict__ bsum) {
    int base = blockIdx.x * 1024;
    int local = 0;
#pragma unroll
    for (int j = 0; j < 4; ++j) {
        int idx = base + threadIdx.x + j * 256;
        if (idx < n) local += deg[idx];
    }
    __shared__ int s[4];
#pragma unroll
    for (int off = 32; off; off >>= 1) local += __shfl_down(local, off, 64);
    if ((threadIdx.x & 63) == 0) s[threadIdx.x >> 6] = local;
    __syncthreads();
    if (threadIdx.x == 0) bsum[blockIdx.x] = s[0] + s[1] + s[2] + s[3];
}

__global__ __launch_bounds__(256) void k_bscan(int* __restrict__ bsum, int nb) {
    __shared__ int s[256];
    int t = threadIdx.x;
    int v = (t < nb) ? bsum[t] : 0;
    s[t] = v;
    __syncthreads();
    for (int off = 1; off < 256; off <<= 1) {
        int u = (t >= off) ? s[t - off] : 0;
        __syncthreads();
        s[t] += u;
        __syncthreads();
    }
    if (t < nb) bsum[t] = s[t] - v;   // exclusive
}

// writes row_ptr, dinv, nself AND pre-seeds cnt = row_ptr (fill's atomic counter)
__global__ __launch_bounds__(256) void k_rowptr(const int* __restrict__ deg,
                                                const int* __restrict__ boff, int n,
                                                int* __restrict__ row_ptr,
                                                int* __restrict__ cnt,
                                                float* __restrict__ dinv,
                                                float* __restrict__ nself) {
    __shared__ int s[256];
    int t = threadIdx.x;
    int base = blockIdx.x * 1024 + t * 4;
    int v0 = (base + 0 < n) ? deg[base + 0] : 0;
    int v1 = (base + 1 < n) ? deg[base + 1] : 0;
    int v2 = (base + 2 < n) ? deg[base + 2] : 0;
    int v3 = (base + 3 < n) ? deg[base + 3] : 0;
    int tot = v0 + v1 + v2 + v3;
    s[t] = tot;
    __syncthreads();
    for (int off = 1; off < 256; off <<= 1) {
        int u = (t >= off) ? s[t - off] : 0;
        __syncthreads();
        s[t] += u;
        __syncthreads();
    }
    int run = boff[blockIdx.x] + ((t == 0) ? 0 : s[t - 1]);
    int vals[4] = {v0, v1, v2, v3};
#pragma unroll
    for (int j = 0; j < 4; ++j) {
        int idx = base + j;
        if (idx < n) {
            row_ptr[idx] = run;
            cnt[idx] = run;
            run += vals[j];
            float df = (float)vals[j] + 1.0f;
            dinv[idx] = rsqrtf(df);
            nself[idx] = 1.0f / df;
        }
    }
    if (blockIdx.x == gridDim.x - 1 && t == 255) row_ptr[n] = boff[blockIdx.x] + s[255];
}

// fill CSR: single packed 8B store per edge {col, wgt bits}; cnt pre-seeded to row_ptr
__global__ void k_fill(const int* __restrict__ ei, int E, int N,
                       const int* __restrict__ flags,
                       int* __restrict__ cnt,
                       const float* __restrict__ dinv,
                       uint2* __restrict__ colwgt) {
    int e = blockIdx.x * blockDim.x + threadIdx.x;
    if (e < E) {
        int is64 = flags[11];
        int s = is64 ? ei[2 * e] : ei[e];
        int d = is64 ? ei[2 * E + 2 * e] : ei[E + e];
        if ((unsigned)d < (unsigned)N) {
            int pos = atomicAdd(&cnt[d], 1);
            int ss = ((unsigned)s < (unsigned)N) ? s : 0;
            float w = dinv[ss] * dinv[d];
            uint2 pk;
            pk.x = (uint_t)ss;
            pk.y = __float_as_uint(w);
            colwgt[pos] = pk;
        }
    }
}

// transpose + canonicalize weights to bf16: W[K x F] -> WT[F x K]
__global__ void k_pack(const void* __restrict__ W1, const void* __restrict__ W2,
                       const void* __restrict__ W3, const void* __restrict__ Wr,
                       const void* __restrict__ Wl, const int* __restrict__ flags,
                       ushort_t* __restrict__ T1, ushort_t* __restrict__ T2,
                       ushort_t* __restrict__ T3, ushort_t* __restrict__ Tr,
                       ushort_t* __restrict__ Tl) {
    int i = blockIdx.x * blockDim.x + threadIdx.x;
    const int SQ = 128 * 128;
    if (i < 4 * SQ) {
        int m = i / SQ, r = i % SQ;
        int k = r / 128, f = r % 128;
        const void* W = (m == 0) ? W1 : (m == 1) ? W2 : (m == 2) ? W3 : Wr;
        ushort_t* T = (m == 0) ? T1 : (m == 1) ? T2 : (m == 2) ? T3 : Tr;
        int fid = (m == 0) ? 1 : (m == 1) ? 3 : (m == 2) ? 5 : 7;
        T[f * 128 + k] = f2bf(loadF(W, (size_t)k * 128 + f, flags[fid]));
    } else if (i < 4 * SQ + 128 * 64) {
        int r = i - 4 * SQ;
        int k = r / 64, f = r % 64;
        Tl[f * 128 + k] = f2bf(loadF(Wl, (size_t)k * 64 + f, flags[9]));
    }
}

// ---------------- GEMM: A[M x 128] @ W[128 x (NCT*16)] ----------------
template <int NCT>
__global__ __launch_bounds__(256) void k_gemm(const void* __restrict__ A, int aFid, int aFix,
                                              const ushort_t* __restrict__ WT,
                                              const void* __restrict__ bias, int bFid,
                                              void* __restrict__ C, int cFix,
                                              int M, const int* __restrict__ flags) {
    const int K = 128;
    const int F = NCT * 16;
    int wave = threadIdx.x >> 6;
    int lane = threadIdx.x & 63;
    int quad = lane >> 4;
    int l16 = lane & 15;
    int rowBase = blockIdx.x * 64 + wave * 16;

    int a16 = (aFid >= 0) ? flags[aFid] : aFix;
    int c16 = cFix;

    int arow = rowBase + l16;
    if (arow >= M) arow = M - 1;

    f32x4 acc[NCT];
#pragma unroll
    for (int c = 0; c < NCT; ++c) acc[c] = (f32x4){0.f, 0.f, 0.f, 0.f};

    const ushort_t* aptr16 = (const ushort_t*)A + (size_t)arow * K + quad * 8;
    const float*    aptr32 = (const float*)A + (size_t)arow * K + quad * 8;

#pragma unroll
    for (int kk = 0; kk < K; kk += 32) {
        bf16x8 a;
        if (a16) {
            a = *(const bf16x8*)(aptr16 + kk);
        } else {
            const f32x4* p = (const f32x4*)(aptr32 + kk);
            f32x4 u0 = p[0], u1 = p[1];
#pragma unroll
            for (int j = 0; j < 4; ++j) {
                BFU e0; e0.u = f2bf(u0[j]); a[j] = e0.h;
                BFU e1; e1.u = f2bf(u1[j]); a[j + 4] = e1.h;
            }
        }
#pragma unroll
        for (int c = 0; c < NCT; ++c) {
            const ushort_t* bp = WT + (size_t)(c * 16 + l16) * K + quad * 8 + kk;
            bf16x8 b = *(const bf16x8*)bp;
            acc[c] = __builtin_amdgcn_mfma_f32_16x16x32_bf16(a, b, acc[c], 0, 0, 0);
        }
    }

    int bf = (bias && bFid >= 0) ? flags[bFid] : 1;
#pragma unroll
    for (int c = 0; c < NCT; ++c) {
        int colg = c * 16 + l16;
        float bv = bias ? loadF(bias, colg, bf) : 0.0f;
#pragma unroll
        for (int r = 0; r < 4; ++r) {
            int row = rowBase + quad * 4 + r;
            if (row < M) {
                float v = acc[c][r] + bv;
                if (c16) ((ushort_t*)C)[(size_t)row * F + colg] = f2bf(v);
                else     ((float*)C)[(size_t)row * F + colg] = v;
            }
        }
    }
}

// ---------------- aggregation: one wave per node, batched-MLP gather ----------------
// H bf16 [n x 128]; packed edge metadata {col,wgt}; bias flag-dtyped; other fp32; Out bf16.
// Metadata preloaded 64-wide (one 8B lane load), broadcast via shfl; H-row gathers
// issued in independent groups of 8 for memory-level parallelism.
__global__ __launch_bounds__(256) void k_agg(const ushort_t* __restrict__ H,
                                             const int* __restrict__ row_ptr,
                                             const uint2* __restrict__ colwgt,
                                             const float* __restrict__ nself,
                                             const void* __restrict__ bias, int bFid,
                                             const float* __restrict__ other,
                                             ushort_t* __restrict__ Out,
                                             int n, const int* __restrict__ flags) {
    int node = (blockIdx.x * blockDim.x + threadIdx.x) >> 6;
    if (node >= n) return;
    int lane = threadIdx.x & 63;
    int f = lane * 2;

    float ns = nself[node];
    size_t nidx = (size_t)node * 128 + f;

    uint_t hv = *(const uint_t*)(H + nidx);
    float a0 = bf2f(hv & 0xffffu) * ns;
    float a1 = bf2f(hv >> 16) * ns;

    int beg = row_ptr[node], end = row_ptr[node + 1];
    for (int bs = beg; bs < end; bs += 64) {
        int rem = end - bs;
        int nb = (rem < 64) ? rem : 64;
        uint2 m = (lane < nb) ? colwgt[bs + lane] : (uint2){0u, 0u};
        int c = (int)m.x;
        float w = __uint_as_float(m.y);

        int j = 0;
        for (; j + 8 <= nb; j += 8) {
            int si[8]; float wi[8]; uint_t vi[8];
#pragma unroll
            for (int q = 0; q < 8; ++q) {
                si[q] = __shfl(c, j + q, 64);
                wi[q] = __shfl(w, j + q, 64);
            }
#pragma unroll
            for (int q = 0; q < 8; ++q)
                vi[q] = *(const uint_t*)(H + (size_t)si[q] * 128 + f);
#pragma unroll
            for (int q = 0; q < 8; ++q) {
                a0 = fmaf(bf2f(vi[q] & 0xffffu), wi[q], a0);
                a1 = fmaf(bf2f(vi[q] >> 16), wi[q], a1);
            }
        }
        for (; j + 4 <= nb; j += 4) {
            int si[4]; float wi[4]; uint_t vi[4];
#pragma unroll
            for (int q = 0; q < 4; ++q) {
                si[q] = __shfl(c, j + q, 64);
                wi[q] = __shfl(w, j + q, 64);
            }
#pragma unroll
            for (int q = 0; q < 4; ++q)
                vi[q] = *(const uint_t*)(H + (size_t)si[q] * 128 + f);
#pragma unroll
            for (int q = 0; q < 4; ++q) {
                a0 = fmaf(bf2f(vi[q] & 0xffffu), wi[q], a0);
                a1 = fmaf(bf2f(vi[q] >> 16), wi[q], a1);
            }
        }
        for (; j < nb; ++j) {
            int sj = __shfl(c, j, 64);
            float wj = __shfl(w, j, 64);
            uint_t v = *(const uint_t*)(H + (size_t)sj * 128 + f);
            a0 = fmaf(bf2f(v & 0xffffu), wj, a0);
            a1 = fmaf(bf2f(v >> 16), wj, a1);
        }
    }

    int bfm = flags[bFid];
    a0 += loadF(bias, f, bfm);
    a1 += loadF(bias, f + 1, bfm);
    if (other) {
        a0 += other[nidx];
        a1 += other[nidx + 1];
    }
    a0 = fmaxf(a0, 0.0f);
    a1 = fmaxf(a1, 0.0f);
    uint_t outv = (uint_t)f2bf(a0) | ((uint_t)f2bf(a1) << 16);
    *(uint_t*)(Out + nidx) = outv;
}

// ---------------- launch ----------------

extern "C" void kernel_launch(void* const* d_in, const int* in_sizes, int n_in,
                              void* d_out, int out_size, void* d_ws, size_t ws_size,
                              hipStream_t stream) {
    const int N = in_sizes[0] / 128;
    const int E = in_sizes[1] / 2;

    const void* x  = d_in[0];
    const int*  ei = (const int*)d_in[1];

    char* ws = (char*)d_ws;
    size_t used = 0;
    auto alloc = [&](size_t bytes) {
        char* p = ws + used;
        used += (bytes + 255) & ~(size_t)255;
        return p;
    };

    int*   flags   = (int*)alloc(64 * 4);
    int*   deg     = (int*)alloc((size_t)N * 4);
    int*   cnt     = (int*)alloc((size_t)N * 4);
    int*   row_ptr = (int*)alloc((size_t)(N + 1) * 4);
    float* dinv    = (float*)alloc((size_t)N * 4);
    float* nself   = (float*)alloc((size_t)N * 4);
    uint2* colwgt  = (uint2*)alloc((size_t)E * 8);
    int*   bsum    = (int*)alloc(256 * 4);
    ushort_t* T1   = (ushort_t*)alloc(128 * 128 * 2);
    ushort_t* T2   = (ushort_t*)alloc(128 * 128 * 2);
    ushort_t* T3   = (ushort_t*)alloc(128 * 128 * 2);
    ushort_t* Tres = (ushort_t*)alloc(128 * 128 * 2);
    ushort_t* Tlin = (ushort_t*)alloc(128 * 64 * 2);

    ushort_t* Hbuf = (ushort_t*)alloc((size_t)N * 128 * 2);  // gather source, bf16
    ushort_t* Act1 = (ushort_t*)alloc((size_t)N * 128 * 2);  // activations, bf16
    ushort_t* Act2 = (ushort_t*)alloc((size_t)N * 128 * 2);
    float*    Xres = (float*)alloc((size_t)N * 128 * 4);     // residual, fp32

    if (used > ws_size) return;

    DetectArgs da;
    for (int i = 0; i < 11; ++i) { da.t[i] = d_in[i == 0 ? 0 : i + 1]; da.elems[i] = in_sizes[i == 0 ? 0 : i + 1]; }
    da.ei = ei;
    da.flags = flags;

    const int B = 256;
    int gZero = (N + B - 1) / B;
    int gE    = (E + B - 1) / B;
    int gPack = (4 * 128 * 128 + 128 * 64 + B - 1) / B;
    int gGemm = (N + 63) / 64;
    int gAgg  = (N + 3) / 4;
    int nb    = (N + 1023) / 1024;

    k_detect<<<1, 64, 0, stream>>>(da);
    k_zero<<<gZero, B, 0, stream>>>(deg, N);
    k_pack<<<gPack, B, 0, stream>>>(d_in[2], d_in[4], d_in[6], d_in[8], d_in[10], flags,
                                    T1, T2, T3, Tres, Tlin);
    k_deg<<<gE, B, 0, stream>>>(ei, E, N, flags, deg);
    k_bsum<<<nb, B, 0, stream>>>(deg, N, bsum);
    k_bscan<<<1, B, 0, stream>>>(bsum, nb);
    k_rowptr<<<nb, B, 0, stream>>>(deg, bsum, N, row_ptr, cnt, dinv, nself);
    k_fill<<<gE, B, 0, stream>>>(ei, E, N, flags, cnt, dinv, colwgt);

    // layer 1: H = x@W1 (bf16) ; Xres = x@Wres + bres (fp32) ; Act1 = relu(agg + b1 + Xres)
    k_gemm<8><<<gGemm, B, 0, stream>>>(x, 0, 0, T1, nullptr, -1, Hbuf, 1, N, flags);
    k_gemm<8><<<gGemm, B, 0, stream>>>(x, 0, 0, Tres, d_in[9], 8, Xres, 0, N, flags);
    k_agg<<<gAgg, B, 0, stream>>>(Hbuf, row_ptr, colwgt, nself, d_in[3], 2,
                                  Xres, Act1, N, flags);

    // layer 2: H = Act1@W2 ; Act2 = relu(agg + b2)
    k_gemm<8><<<gGemm, B, 0, stream>>>(Act1, -1, 1, T2, nullptr, -1, Hbuf, 1, N, flags);
    k_agg<<<gAgg, B, 0, stream>>>(Hbuf, row_ptr, colwgt, nself, d_in[5], 4,
                                  nullptr, Act2, N, flags);

    // layer 3: H = Act2@W3 ; Act1 = relu(agg + b3)   (reuse Act1)
    k_gemm<8><<<gGemm, B, 0, stream>>>(Act2, -1, 1, T3, nullptr, -1, Hbuf, 1, N, flags);
    k_agg<<<gAgg, B, 0, stream>>>(Hbuf, row_ptr, colwgt, nself, d_in[7], 6,
                                  nullptr, Act1, N, flags);

    // final: out = Act1@Wlin + blin (fp32 out)
    k_gemm<4><<<gGemm, B, 0, stream>>>(Act1, -1, 1, Tlin, d_in[11], 10,
                                       d_out, 0, N, flags);
}